// Round 3
// baseline (130.510 us; speedup 1.0000x reference)
//
#include <hip/hip_runtime.h>

#define BB 128
#define NN 128
#define EE 32

// ws layout (ints): sat[0..127] (f32 bits, unsigned atomicMin), cnt at [128].
// kernel_launch memsets bytes 0..515 to 0x7F each call:
//   sat[b] = 0x7F7F7F7F = 3.39e38f  (+inf sentinel; all real vals <= 1.0)
//   cnt    = 0x7F7F7F7F  (counter base; last block sees old-base == 511)
#define CNT_BASE 0x7F7F7F7Fu

// ---------------------------------------------------------------------------
// Fused kernel. Grid 512 = 128 b x 4 q. Block 256 (4 waves).
// Phase A: encode all 128 items of batch b into LDS (hy, iso; hx for own 32 i).
//          32 lanes per item (lane = neuron e), 8 items/pass, 16 passes.
// Phase B: per (i, s=j-lane): sum_j min(iso_j, sigmoid(sum_k relu(hx+hy+bs1)*Ws2 + bs2))
// Phase C: block min over i -> atomicMin(sat[b]); last block does the mean.
// ---------------------------------------------------------------------------
__global__ __launch_bounds__(256, 2) void ltn_fused(
    const float* __restrict__ boxes, const int* __restrict__ classes,
    const float* __restrict__ scores, const int* __restrict__ num_objects,
    const float* __restrict__ W1, const float* __restrict__ b1,
    const float* __restrict__ W2, const float* __restrict__ b2,
    const float* __restrict__ Wo1, const float* __restrict__ bo1,
    const float* __restrict__ Wo2, const float* __restrict__ bo2,
    const float* __restrict__ Ws1, const float* __restrict__ bs1,
    const float* __restrict__ Ws2, const float* __restrict__ bs2,
    unsigned* __restrict__ ws, float* __restrict__ out, int nblocks)
{
    __shared__ float hyS[128 * 36];   // row j, stride 36 floats (144B, 16B-aligned)
    __shared__ float isoS[128];
    __shared__ float hxS[32 * 33];    // this block's 32 i-rows
    __shared__ float wred[4];
    __shared__ int lastFlag;
    __shared__ float r1[4], r2[4];

    const int t = threadIdx.x;
    const int b = blockIdx.x >> 2;
    const int q = blockIdx.x & 3;

    // ---------------- Phase A: encode ----------------
#pragma unroll 1
    for (int pass = 0; pass < 16; ++pass) {
        const int il = pass * 8 + (t >> 5);   // local item 0..127
        const int e  = t & 31;
        const int item = b * 128 + il;

        const float* bx = boxes + item * 4;
        const float c0 = bx[0];
        const float c1 = bx[1];
        const float c2 = bx[2];
        const float c3 = bx[3];
        const float c4 = (float)classes[item];
        const float c5 = scores[item];

        // layer 1: h1 = relu(c @ W1 + b1)
        float h1 = b1[e];
        h1 = fmaf(c0, W1[0 * 32 + e], h1);
        h1 = fmaf(c1, W1[1 * 32 + e], h1);
        h1 = fmaf(c2, W1[2 * 32 + e], h1);
        h1 = fmaf(c3, W1[3 * 32 + e], h1);
        h1 = fmaf(c4, W1[4 * 32 + e], h1);
        h1 = fmaf(c5, W1[5 * 32 + e], h1);
        h1 = fmaxf(h1, 0.f);

        // layer 2: enc = h1 @ W2 + b2
        float enc = b2[e];
#pragma unroll
        for (int k = 0; k < 32; k++)
            enc = fmaf(__shfl(h1, k, 32), W2[k * 32 + e], enc);

        // heads
        float u = bo1[e];
        float hx = 0.f, hy = 0.f;
#pragma unroll
        for (int k = 0; k < 32; k++) {
            const float ek = __shfl(enc, k, 32);
            u  = fmaf(ek, Wo1[k * 32 + e], u);
            hx = fmaf(ek, Ws1[k * 32 + e], hx);
            hy = fmaf(ek, Ws1[(32 + k) * 32 + e], hy);
        }
        u = fmaxf(u, 0.f);

        float v = u * Wo2[e];
#pragma unroll
        for (int off = 16; off >= 1; off >>= 1) v += __shfl_xor(v, off, 32);

        hyS[il * 36 + e] = hy;
        if ((il >> 5) == q) hxS[(il & 31) * 33 + e] = hx;
        if (e == 0) isoS[il] = 1.f / (1.f + __expf(-(v + bo2[0])));
    }
    __syncthreads();

    // ---------------- Phase B: pairs ----------------
    const int nb = num_objects[b];
    const int il = t >> 3;            // 0..31
    const int i  = q * 32 + il;
    const int s  = t & 7;

    float hxb[32];
#pragma unroll
    for (int k = 0; k < 32; k++) hxb[k] = hxS[il * 33 + k] + bs1[k];
    float w2[32];
#pragma unroll
    for (int k = 0; k < 32; k++) w2[k] = Ws2[k];    // wave-uniform -> SGPRs
    const float bbias = bs2[0];

    float acc = 0.f;
    for (int j = s; j < nb; j += 8) {
        const float4* hr4 = (const float4*)(hyS + j * 36);
        float d = bbias;
#pragma unroll
        for (int kk = 0; kk < 8; kk++) {
            const float4 h = hr4[kk];
            d = fmaf(fmaxf(hxb[4 * kk + 0] + h.x, 0.f), w2[4 * kk + 0], d);
            d = fmaf(fmaxf(hxb[4 * kk + 1] + h.y, 0.f), w2[4 * kk + 1], d);
            d = fmaf(fmaxf(hxb[4 * kk + 2] + h.z, 0.f), w2[4 * kk + 2], d);
            d = fmaf(fmaxf(hxb[4 * kk + 3] + h.w, 0.f), w2[4 * kk + 3], d);
        }
        const float same = 1.f / (1.f + __expf(-d));
        acc += fminf(isoS[j], same);
    }
    acc += __shfl_xor(acc, 1);
    acc += __shfl_xor(acc, 2);
    acc += __shfl_xor(acc, 4);

    const float exists = acc / (float)(nb > 1 ? nb : 1);
    const float outer = fmaxf(1.f - isoS[i], exists);
    float val = (i < nb) ? outer : 1.f;

    val = fminf(val, __shfl_xor(val, 8));
    val = fminf(val, __shfl_xor(val, 16));
    val = fminf(val, __shfl_xor(val, 32));
    if ((t & 63) == 0) wred[t >> 6] = val;
    __syncthreads();

    // ---------------- Phase C: cross-block reduction ----------------
    if (t == 0) {
        const float m = fminf(fminf(wred[0], wred[1]), fminf(wred[2], wred[3]));
        atomicMin(ws + b, __float_as_uint(m));   // vals >= 0: uint order == float order
        __threadfence();
        const unsigned old = __hip_atomic_fetch_add(ws + 128, 1u,
                                                    __ATOMIC_ACQ_REL, __HIP_MEMORY_SCOPE_AGENT);
        lastFlag = ((old - CNT_BASE) == (unsigned)(nblocks - 1)) ? 1 : 0;
    }
    __syncthreads();

    if (lastFlag) {
        float contrib = 0.f, vcnt = 0.f;
        if (t < 128) {
            const int nbt = num_objects[t];
            const unsigned sbits = __hip_atomic_load(ws + t, __ATOMIC_RELAXED,
                                                     __HIP_MEMORY_SCOPE_AGENT);
            const float sat = __uint_as_float(sbits);
            const float valid = (nbt > 0) ? 1.f : 0.f;
            contrib = sat * valid;
            vcnt = valid;
        }
#pragma unroll
        for (int off = 1; off < 64; off <<= 1) {
            contrib += __shfl_xor(contrib, off);
            vcnt += __shfl_xor(vcnt, off);
        }
        if ((t & 63) == 0) { r1[t >> 6] = contrib; r2[t >> 6] = vcnt; }
        __syncthreads();
        if (t == 0) {
            const float sc = r1[0] + r1[1] + r1[2] + r1[3];
            const float cn = r2[0] + r2[1] + r2[2] + r2[3];
            out[0] = (cn > 0.f) ? (sc / cn) : 1.f;
        }
    }
}

extern "C" void kernel_launch(void* const* d_in, const int* in_sizes, int n_in,
                              void* d_out, int out_size, void* d_ws, size_t ws_size,
                              hipStream_t stream)
{
    const float* boxes       = (const float*)d_in[0];
    const int*   classes     = (const int*)d_in[1];
    const float* scores      = (const float*)d_in[2];
    const int*   num_objects = (const int*)d_in[3];
    const float* W1  = (const float*)d_in[4];
    const float* b1  = (const float*)d_in[5];
    const float* W2  = (const float*)d_in[6];
    const float* b2  = (const float*)d_in[7];
    const float* Wo1 = (const float*)d_in[8];
    const float* bo1 = (const float*)d_in[9];
    const float* Wo2 = (const float*)d_in[10];
    const float* bo2 = (const float*)d_in[11];
    const float* Ws1 = (const float*)d_in[12];
    const float* bs1 = (const float*)d_in[13];
    const float* Ws2 = (const float*)d_in[14];
    const float* bs2 = (const float*)d_in[15];

    unsigned* ws  = (unsigned*)d_ws;
    float*    out = (float*)d_out;

    // init sat[128] + cnt to 0x7F7F7F7F (sentinel / counter base)
    hipMemsetAsync(ws, 0x7F, 129 * sizeof(unsigned), stream);

    const int nblocks = 128 * 4;
    ltn_fused<<<nblocks, 256, 0, stream>>>(boxes, classes, scores, num_objects,
                                           W1, b1, W2, b2, Wo1, bo1, Wo2, bo2,
                                           Ws1, bs1, Ws2, bs2, ws, out, nblocks);
}

// Round 4
// 113.804 us; speedup vs baseline: 1.1468x; 1.1468x over previous
//
#include <hip/hip_runtime.h>

#define BB 128
#define NN 128
#define EE 32

// ws layout in 4-byte elements:
//  sat  : [0, 128)        f32-bits, unsigned atomicMin (init 0x7F7F7F7F)
//  cnt  : [128]           completion counter (init 0x7F7F7F7F)
//  hx   : [HX_OFF, +16384*32)  f32
//  hy   : [HY_OFF, +16384*32)  f32
//  iso  : [ISO_OFF, +16384)    f32
#define SAT_OFF 0
#define CNT_OFF 128
#define HX_OFF  256
#define HY_OFF  (HX_OFF + 16384 * 32)
#define ISO_OFF (HY_OFF + 16384 * 32)
#define CNT_BASE 0x7F7F7F7Fu

// ---------------------------------------------------------------------------
// Encode: 2048 blocks x 256 threads, 8 items/block, 32 lanes per item (lane=e).
// All weights staged to LDS once per block; h1/enc round-trip through an LDS
// row (broadcast reads within the half-wave; no barrier needed — wave-order).
// ---------------------------------------------------------------------------
__global__ __launch_bounds__(256) void encode_kernel(
    const float* __restrict__ boxes, const int* __restrict__ classes,
    const float* __restrict__ scores,
    const float* __restrict__ W1, const float* __restrict__ b1,
    const float* __restrict__ W2, const float* __restrict__ b2,
    const float* __restrict__ Wo1, const float* __restrict__ bo1,
    const float* __restrict__ Wo2, const float* __restrict__ bo2,
    const float* __restrict__ Ws1, float* __restrict__ ws)
{
    // LDS layout (floats):
    //    0: W1   192      |  192: b1  32  |  224: W2  1024 | 1248: b2  32
    // 1280: Wo1 1024      | 2304: bo1 32  | 2336: Wo2 32   | 2368: bo2 1(+3)
    // 2372: h1/enc rows 8*40 (rows 16B-aligned)
    // 2692: Ws1 2048
    __shared__ float sm[4740];   // 18960 B -> 8 blocks/CU possible

    const int t = threadIdx.x;

    // ---- stage weights (coalesced float4) ----
    ((float4*)(sm + 224))[t]        = ((const float4*)W2)[t];          // 1024
    ((float4*)(sm + 1280))[t]       = ((const float4*)Wo1)[t];         // 1024
    ((float4*)(sm + 2692))[t]       = ((const float4*)Ws1)[t];         // 2048
    ((float4*)(sm + 2692))[t + 256] = ((const float4*)Ws1)[t + 256];
    if (t < 48) ((float4*)sm)[t] = ((const float4*)W1)[t];             // 192
    if (t < 32) {
        sm[192 + t]  = b1[t];
        sm[1248 + t] = b2[t];
        sm[2304 + t] = bo1[t];
        sm[2336 + t] = Wo2[t];
    }
    if (t == 0) sm[2368] = bo2[0];
    __syncthreads();

    const int il = t >> 5;             // local item 0..7
    const int e  = t & 31;
    const int item = blockIdx.x * 8 + il;

    // features
    const float4 bx = ((const float4*)boxes)[item];
    const float c4 = (float)classes[item];
    const float c5 = scores[item];

    // layer 1
    float h1 = sm[192 + e];
    h1 = fmaf(bx.x, sm[0 * 32 + e], h1);
    h1 = fmaf(bx.y, sm[1 * 32 + e], h1);
    h1 = fmaf(bx.z, sm[2 * 32 + e], h1);
    h1 = fmaf(bx.w, sm[3 * 32 + e], h1);
    h1 = fmaf(c4,   sm[4 * 32 + e], h1);
    h1 = fmaf(c5,   sm[5 * 32 + e], h1);
    h1 = fmaxf(h1, 0.f);

    float* row = sm + 2372 + il * 40;  // 16B-aligned row, private to half-wave
    row[e] = h1;

    // layer 2: enc = h1 @ W2 + b2, 4 accumulator chains
    float a0 = 0.f, a1 = 0.f, a2 = 0.f, a3 = 0.f;
#pragma unroll
    for (int kk = 0; kk < 8; kk++) {
        const float4 h = *(const float4*)(row + kk * 4);  // broadcast
        a0 = fmaf(h.x, sm[224 + (4 * kk + 0) * 32 + e], a0);
        a1 = fmaf(h.y, sm[224 + (4 * kk + 1) * 32 + e], a1);
        a2 = fmaf(h.z, sm[224 + (4 * kk + 2) * 32 + e], a2);
        a3 = fmaf(h.w, sm[224 + (4 * kk + 3) * 32 + e], a3);
    }
    const float enc = ((a0 + a1) + (a2 + a3)) + sm[1248 + e];
    row[e] = enc;   // safe: all h1 reads above precede this in wave order

    // heads: u = relu(enc@Wo1+bo1), hx = enc@Ws1[:32], hy = enc@Ws1[32:]
    float u = sm[2304 + e];
    float hx = 0.f, hy = 0.f;
#pragma unroll
    for (int kk = 0; kk < 8; kk++) {
        const float4 ec = *(const float4*)(row + kk * 4);  // broadcast
        const int k0 = 4 * kk;
        u  = fmaf(ec.x, sm[1280 + (k0 + 0) * 32 + e], u);
        u  = fmaf(ec.y, sm[1280 + (k0 + 1) * 32 + e], u);
        u  = fmaf(ec.z, sm[1280 + (k0 + 2) * 32 + e], u);
        u  = fmaf(ec.w, sm[1280 + (k0 + 3) * 32 + e], u);
        hx = fmaf(ec.x, sm[2692 + (k0 + 0) * 32 + e], hx);
        hx = fmaf(ec.y, sm[2692 + (k0 + 1) * 32 + e], hx);
        hx = fmaf(ec.z, sm[2692 + (k0 + 2) * 32 + e], hx);
        hx = fmaf(ec.w, sm[2692 + (k0 + 3) * 32 + e], hx);
        hy = fmaf(ec.x, sm[2692 + (32 + k0 + 0) * 32 + e], hy);
        hy = fmaf(ec.y, sm[2692 + (32 + k0 + 1) * 32 + e], hy);
        hy = fmaf(ec.z, sm[2692 + (32 + k0 + 2) * 32 + e], hy);
        hy = fmaf(ec.w, sm[2692 + (32 + k0 + 3) * 32 + e], hy);
    }
    u = fmaxf(u, 0.f);

    float v = u * sm[2336 + e];
    v += __shfl_xor(v, 16, 32);
    v += __shfl_xor(v, 8, 32);
    v += __shfl_xor(v, 4, 32);
    v += __shfl_xor(v, 2, 32);
    v += __shfl_xor(v, 1, 32);

    ws[HX_OFF + item * 32 + e] = hx;
    ws[HY_OFF + item * 32 + e] = hy;
    if (e == 0)
        ws[ISO_OFF + item] = 1.f / (1.f + __expf(-(v + sm[2368])));
}

// ---------------------------------------------------------------------------
// Pairs: grid 512 = 128 b x 4 q; block 256 = 32 i's x 8 j-lanes.
// exists_i = (1/n) * sum_{j<nb} min(iso_j, sigmoid(sum_k relu(hx+hy+bs1)*Ws2+bs2))
// outer_i = max(1-iso_i, exists_i); sat_b = min over i<nb; last block -> mean.
// ---------------------------------------------------------------------------
__global__ __launch_bounds__(256) void pairs_kernel(
    const float* __restrict__ bs1, const float* __restrict__ Ws2,
    const float* __restrict__ bs2, const int* __restrict__ num_objects,
    float* __restrict__ ws, float* __restrict__ out, int nblocks)
{
    __shared__ float hyS[128 * 36];   // stride 36 floats: rows 16B-aligned
    __shared__ float isoS[128];
    __shared__ float wred[4];
    __shared__ int lastFlag;
    __shared__ float r1[4], r2[4];

    const int t = threadIdx.x;
    const int b = blockIdx.x >> 2;
    const int q = blockIdx.x & 3;

    // stage hy tile (float4) + isobj
    const float4* hyg4 = (const float4*)(ws + HY_OFF + b * 128 * 32);
#pragma unroll
    for (int it = 0; it < 4; it++) {
        const int idx = t + it * 256;                  // float4 idx 0..1023
        ((float4*)(hyS + (idx >> 3) * 36))[idx & 7] = hyg4[idx];
    }
    if (t < 128) isoS[t] = ws[ISO_OFF + b * 128 + t];
    __syncthreads();

    const int nb = num_objects[b];
    const int i = q * 32 + (t >> 3);
    const int s = t & 7;

    float hxb[32];
    const float* hxg = ws + HX_OFF + (b * 128 + i) * 32;
#pragma unroll
    for (int k = 0; k < 32; k++) hxb[k] = hxg[k] + bs1[k];
    float w2[32];
#pragma unroll
    for (int k = 0; k < 32; k++) w2[k] = Ws2[k];       // wave-uniform
    const float bbias = bs2[0];

    float acc = 0.f;
    for (int j = s; j < nb; j += 8) {
        const float4* hr4 = (const float4*)(hyS + j * 36);
        float d0 = bbias, d1 = 0.f, d2 = 0.f, d3 = 0.f;
#pragma unroll
        for (int kk = 0; kk < 8; kk++) {
            const float4 h = hr4[kk];
            const int k0 = 4 * kk;
            d0 = fmaf(fmaxf(hxb[k0 + 0] + h.x, 0.f), w2[k0 + 0], d0);
            d1 = fmaf(fmaxf(hxb[k0 + 1] + h.y, 0.f), w2[k0 + 1], d1);
            d2 = fmaf(fmaxf(hxb[k0 + 2] + h.z, 0.f), w2[k0 + 2], d2);
            d3 = fmaf(fmaxf(hxb[k0 + 3] + h.w, 0.f), w2[k0 + 3], d3);
        }
        const float d = (d0 + d1) + (d2 + d3);
        const float same = 1.f / (1.f + __expf(-d));
        acc += fminf(isoS[j], same);
    }
    acc += __shfl_xor(acc, 1);
    acc += __shfl_xor(acc, 2);
    acc += __shfl_xor(acc, 4);

    const float exists = acc / (float)(nb > 1 ? nb : 1);
    const float outer = fmaxf(1.f - isoS[i], exists);
    float val = (i < nb) ? outer : 1.f;

    val = fminf(val, __shfl_xor(val, 8));
    val = fminf(val, __shfl_xor(val, 16));
    val = fminf(val, __shfl_xor(val, 32));
    if ((t & 63) == 0) wred[t >> 6] = val;
    __syncthreads();

    if (t == 0) {
        const float m = fminf(fminf(wred[0], wred[1]), fminf(wred[2], wred[3]));
        atomicMin((unsigned*)ws + SAT_OFF + b, __float_as_uint(m)); // vals >= 0
        __threadfence();
        const unsigned old = __hip_atomic_fetch_add((unsigned*)ws + CNT_OFF, 1u,
                                                    __ATOMIC_ACQ_REL, __HIP_MEMORY_SCOPE_AGENT);
        lastFlag = ((old - CNT_BASE) == (unsigned)(nblocks - 1)) ? 1 : 0;
    }
    __syncthreads();

    if (lastFlag) {
        float contrib = 0.f, vcnt = 0.f;
        if (t < 128) {
            const int nbt = num_objects[t];
            const unsigned sbits = __hip_atomic_load((unsigned*)ws + SAT_OFF + t,
                                                     __ATOMIC_RELAXED, __HIP_MEMORY_SCOPE_AGENT);
            const float sat = __uint_as_float(sbits);
            const float valid = (nbt > 0) ? 1.f : 0.f;
            contrib = sat * valid;
            vcnt = valid;
        }
#pragma unroll
        for (int off = 1; off < 64; off <<= 1) {
            contrib += __shfl_xor(contrib, off);
            vcnt += __shfl_xor(vcnt, off);
        }
        if ((t & 63) == 0) { r1[t >> 6] = contrib; r2[t >> 6] = vcnt; }
        __syncthreads();
        if (t == 0) {
            const float sc = r1[0] + r1[1] + r1[2] + r1[3];
            const float cn = r2[0] + r2[1] + r2[2] + r2[3];
            out[0] = (cn > 0.f) ? (sc / cn) : 1.f;
        }
    }
}

extern "C" void kernel_launch(void* const* d_in, const int* in_sizes, int n_in,
                              void* d_out, int out_size, void* d_ws, size_t ws_size,
                              hipStream_t stream)
{
    const float* boxes       = (const float*)d_in[0];
    const int*   classes     = (const int*)d_in[1];
    const float* scores      = (const float*)d_in[2];
    const int*   num_objects = (const int*)d_in[3];
    const float* W1  = (const float*)d_in[4];
    const float* b1  = (const float*)d_in[5];
    const float* W2  = (const float*)d_in[6];
    const float* b2  = (const float*)d_in[7];
    const float* Wo1 = (const float*)d_in[8];
    const float* bo1 = (const float*)d_in[9];
    const float* Wo2 = (const float*)d_in[10];
    const float* bo2 = (const float*)d_in[11];
    const float* Ws1 = (const float*)d_in[12];
    const float* bs1 = (const float*)d_in[13];
    const float* Ws2 = (const float*)d_in[14];
    const float* bs2 = (const float*)d_in[15];

    float* ws  = (float*)d_ws;
    float* out = (float*)d_out;

    // init sat[128] + cnt to 0x7F7F7F7F (min-sentinel / counter base)
    hipMemsetAsync(ws, 0x7F, 129 * sizeof(float), stream);

    encode_kernel<<<2048, 256, 0, stream>>>(boxes, classes, scores,
                                            W1, b1, W2, b2, Wo1, bo1, Wo2, bo2,
                                            Ws1, ws);
    const int nblocks = 128 * 4;
    pairs_kernel<<<nblocks, 256, 0, stream>>>(bs1, Ws2, bs2, num_objects,
                                              ws, out, nblocks);
}

// Round 5
// 112.034 us; speedup vs baseline: 1.1649x; 1.0158x over previous
//
#include <hip/hip_runtime.h>

#define BB 128
#define NN 128
#define EE 32

// ws layout in 4-byte elements:
//  sat  : [0, 128)        f32-bits, unsigned atomicMin (init 0x7F7F7F7F by encode blk0)
//  cnt  : [128]           completion counter (init 0 by encode blk0)
//  hx   : [HX_OFF, +16384*32)  f32
//  hy   : [HY_OFF, +16384*32)  f32
//  iso  : [ISO_OFF, +16384)    f32
#define SAT_OFF 0
#define CNT_OFF 128
#define HX_OFF  256
#define HY_OFF  (HX_OFF + 16384 * 32)
#define ISO_OFF (HY_OFF + 16384 * 32)

// ---------------------------------------------------------------------------
// Encode: 2048 blocks x 256 threads, 8 items/block, 32 lanes per item (lane=e).
// Weights staged to LDS once per block; h1/enc round-trip through an LDS row
// (broadcast reads within the half-wave; wave-order makes it barrier-free).
// Block 0 additionally initializes sat[]/cnt for the pairs kernel.
// ---------------------------------------------------------------------------
__global__ __launch_bounds__(256) void encode_kernel(
    const float* __restrict__ boxes, const int* __restrict__ classes,
    const float* __restrict__ scores,
    const float* __restrict__ W1, const float* __restrict__ b1,
    const float* __restrict__ W2, const float* __restrict__ b2,
    const float* __restrict__ Wo1, const float* __restrict__ bo1,
    const float* __restrict__ Wo2, const float* __restrict__ bo2,
    const float* __restrict__ Ws1, float* __restrict__ ws)
{
    // LDS layout (floats):
    //    0: W1   192      |  192: b1  32  |  224: W2  1024 | 1248: b2  32
    // 1280: Wo1 1024      | 2304: bo1 32  | 2336: Wo2 32   | 2368: bo2 1(+3)
    // 2372: h1/enc rows 8*40 (rows 16B-aligned)
    // 2692: Ws1 2048
    __shared__ float sm[4740];

    const int t = threadIdx.x;

    if (blockIdx.x == 0) {            // one-time init for pairs kernel
        if (t < 128) ((unsigned*)ws)[SAT_OFF + t] = 0x7F7F7F7Fu; // +big sentinel
        if (t == 128) ((unsigned*)ws)[CNT_OFF] = 0u;
    }

    // ---- stage weights (coalesced float4) ----
    ((float4*)(sm + 224))[t]        = ((const float4*)W2)[t];          // 1024
    ((float4*)(sm + 1280))[t]       = ((const float4*)Wo1)[t];         // 1024
    ((float4*)(sm + 2692))[t]       = ((const float4*)Ws1)[t];         // 2048
    ((float4*)(sm + 2692))[t + 256] = ((const float4*)Ws1)[t + 256];
    if (t < 48) ((float4*)sm)[t] = ((const float4*)W1)[t];             // 192
    if (t < 32) {
        sm[192 + t]  = b1[t];
        sm[1248 + t] = b2[t];
        sm[2304 + t] = bo1[t];
        sm[2336 + t] = Wo2[t];
    }
    if (t == 0) sm[2368] = bo2[0];
    __syncthreads();

    const int il = t >> 5;             // local item 0..7
    const int e  = t & 31;
    const int item = blockIdx.x * 8 + il;

    // features
    const float4 bx = ((const float4*)boxes)[item];
    const float c4 = (float)classes[item];
    const float c5 = scores[item];

    // layer 1
    float h1 = sm[192 + e];
    h1 = fmaf(bx.x, sm[0 * 32 + e], h1);
    h1 = fmaf(bx.y, sm[1 * 32 + e], h1);
    h1 = fmaf(bx.z, sm[2 * 32 + e], h1);
    h1 = fmaf(bx.w, sm[3 * 32 + e], h1);
    h1 = fmaf(c4,   sm[4 * 32 + e], h1);
    h1 = fmaf(c5,   sm[5 * 32 + e], h1);
    h1 = fmaxf(h1, 0.f);

    float* row = sm + 2372 + il * 40;  // 16B-aligned row, private to half-wave
    row[e] = h1;

    // layer 2: enc = h1 @ W2 + b2, 4 accumulator chains
    float a0 = 0.f, a1 = 0.f, a2 = 0.f, a3 = 0.f;
#pragma unroll
    for (int kk = 0; kk < 8; kk++) {
        const float4 h = *(const float4*)(row + kk * 4);  // broadcast
        a0 = fmaf(h.x, sm[224 + (4 * kk + 0) * 32 + e], a0);
        a1 = fmaf(h.y, sm[224 + (4 * kk + 1) * 32 + e], a1);
        a2 = fmaf(h.z, sm[224 + (4 * kk + 2) * 32 + e], a2);
        a3 = fmaf(h.w, sm[224 + (4 * kk + 3) * 32 + e], a3);
    }
    const float enc = ((a0 + a1) + (a2 + a3)) + sm[1248 + e];
    row[e] = enc;   // safe: all h1 reads above precede this in wave order

    // heads: u = relu(enc@Wo1+bo1), hx = enc@Ws1[:32], hy = enc@Ws1[32:]
    float u = sm[2304 + e];
    float hx = 0.f, hy = 0.f;
#pragma unroll
    for (int kk = 0; kk < 8; kk++) {
        const float4 ec = *(const float4*)(row + kk * 4);  // broadcast
        const int k0 = 4 * kk;
        u  = fmaf(ec.x, sm[1280 + (k0 + 0) * 32 + e], u);
        u  = fmaf(ec.y, sm[1280 + (k0 + 1) * 32 + e], u);
        u  = fmaf(ec.z, sm[1280 + (k0 + 2) * 32 + e], u);
        u  = fmaf(ec.w, sm[1280 + (k0 + 3) * 32 + e], u);
        hx = fmaf(ec.x, sm[2692 + (k0 + 0) * 32 + e], hx);
        hx = fmaf(ec.y, sm[2692 + (k0 + 1) * 32 + e], hx);
        hx = fmaf(ec.z, sm[2692 + (k0 + 2) * 32 + e], hx);
        hx = fmaf(ec.w, sm[2692 + (k0 + 3) * 32 + e], hx);
        hy = fmaf(ec.x, sm[2692 + (32 + k0 + 0) * 32 + e], hy);
        hy = fmaf(ec.y, sm[2692 + (32 + k0 + 1) * 32 + e], hy);
        hy = fmaf(ec.z, sm[2692 + (32 + k0 + 2) * 32 + e], hy);
        hy = fmaf(ec.w, sm[2692 + (32 + k0 + 3) * 32 + e], hy);
    }
    u = fmaxf(u, 0.f);

    float v = u * sm[2336 + e];
    v += __shfl_xor(v, 16, 32);
    v += __shfl_xor(v, 8, 32);
    v += __shfl_xor(v, 4, 32);
    v += __shfl_xor(v, 2, 32);
    v += __shfl_xor(v, 1, 32);

    ws[HX_OFF + item * 32 + e] = hx;
    ws[HY_OFF + item * 32 + e] = hy;
    if (e == 0)
        ws[ISO_OFF + item] = 1.f / (1.f + __expf(-(v + sm[2368])));
}

// ---------------------------------------------------------------------------
// Pairs: grid 512 = 128 b x 4 q; block 256 = 32 i's x 8 j-lanes.
// exists_i = (1/n) * sum_{j<nb} min(iso_j, sigmoid(sum_k relu(hx+hy+bs1)*Ws2+bs2))
// outer_i = max(1-iso_i, exists_i); sat_b = min over i<nb; last block -> mean.
// ---------------------------------------------------------------------------
__global__ __launch_bounds__(256) void pairs_kernel(
    const float* __restrict__ bs1, const float* __restrict__ Ws2,
    const float* __restrict__ bs2, const int* __restrict__ num_objects,
    float* __restrict__ ws, float* __restrict__ out, int nblocks)
{
    __shared__ float hyS[128 * 36];   // stride 36 floats: rows 16B-aligned
    __shared__ float hxS[32 * 36];    // this block's 32 i-rows
    __shared__ float isoS[128];
    __shared__ float wred[4];
    __shared__ int lastFlag;
    __shared__ float r1[4], r2[4];

    const int t = threadIdx.x;
    const int b = blockIdx.x >> 2;
    const int q = blockIdx.x & 3;

    // stage hy tile + hx tile (float4) + isobj
    const float4* hyg4 = (const float4*)(ws + HY_OFF + b * 128 * 32);
#pragma unroll
    for (int it = 0; it < 4; it++) {
        const int idx = t + it * 256;                  // float4 idx 0..1023
        ((float4*)(hyS + (idx >> 3) * 36))[idx & 7] = hyg4[idx];
    }
    {
        const float4* hxg4 = (const float4*)(ws + HX_OFF + (b * 128 + q * 32) * 32);
        ((float4*)(hxS + (t >> 3) * 36))[t & 7] = hxg4[t];   // 256 f4 = 1024 floats
    }
    if (t < 128) isoS[t] = ws[ISO_OFF + b * 128 + t];
    __syncthreads();

    const int nb = num_objects[b];
    const int il = t >> 3;            // 0..31
    const int i  = q * 32 + il;
    const int s  = t & 7;

    float hxb[32];
#pragma unroll
    for (int kk = 0; kk < 8; kk++) {
        const float4 h = ((const float4*)(hxS + il * 36))[kk];
        hxb[4 * kk + 0] = h.x + bs1[4 * kk + 0];
        hxb[4 * kk + 1] = h.y + bs1[4 * kk + 1];
        hxb[4 * kk + 2] = h.z + bs1[4 * kk + 2];
        hxb[4 * kk + 3] = h.w + bs1[4 * kk + 3];
    }
    float w2[32];
#pragma unroll
    for (int k = 0; k < 32; k++) w2[k] = Ws2[k];       // wave-uniform -> SGPR
    const float bbias = bs2[0];

    float acc = 0.f;
    for (int j = s; j < nb; j += 8) {
        const float4* hr4 = (const float4*)(hyS + j * 36);
        float d0 = bbias, d1 = 0.f, d2 = 0.f, d3 = 0.f;
#pragma unroll
        for (int kk = 0; kk < 8; kk++) {
            const float4 h = hr4[kk];
            const int k0 = 4 * kk;
            d0 = fmaf(fmaxf(hxb[k0 + 0] + h.x, 0.f), w2[k0 + 0], d0);
            d1 = fmaf(fmaxf(hxb[k0 + 1] + h.y, 0.f), w2[k0 + 1], d1);
            d2 = fmaf(fmaxf(hxb[k0 + 2] + h.z, 0.f), w2[k0 + 2], d2);
            d3 = fmaf(fmaxf(hxb[k0 + 3] + h.w, 0.f), w2[k0 + 3], d3);
        }
        const float d = (d0 + d1) + (d2 + d3);
        const float same = 1.f / (1.f + __expf(-d));
        acc += fminf(isoS[j], same);
    }
    acc += __shfl_xor(acc, 1);
    acc += __shfl_xor(acc, 2);
    acc += __shfl_xor(acc, 4);

    const float exists = acc / (float)(nb > 1 ? nb : 1);
    const float outer = fmaxf(1.f - isoS[i], exists);
    float val = (i < nb) ? outer : 1.f;

    val = fminf(val, __shfl_xor(val, 8));
    val = fminf(val, __shfl_xor(val, 16));
    val = fminf(val, __shfl_xor(val, 32));
    if ((t & 63) == 0) wred[t >> 6] = val;
    __syncthreads();

    if (t == 0) {
        const float m = fminf(fminf(wred[0], wred[1]), fminf(wred[2], wred[3]));
        atomicMin((unsigned*)ws + SAT_OFF + b, __float_as_uint(m)); // vals >= 0
        __threadfence();
        const unsigned old = __hip_atomic_fetch_add((unsigned*)ws + CNT_OFF, 1u,
                                                    __ATOMIC_ACQ_REL, __HIP_MEMORY_SCOPE_AGENT);
        lastFlag = (old == (unsigned)(nblocks - 1)) ? 1 : 0;
    }
    __syncthreads();

    if (lastFlag) {
        float contrib = 0.f, vcnt = 0.f;
        if (t < 128) {
            const int nbt = num_objects[t];
            const unsigned sbits = __hip_atomic_load((unsigned*)ws + SAT_OFF + t,
                                                     __ATOMIC_RELAXED, __HIP_MEMORY_SCOPE_AGENT);
            const float sat = __uint_as_float(sbits);
            const float valid = (nbt > 0) ? 1.f : 0.f;
            contrib = sat * valid;
            vcnt = valid;
        }
#pragma unroll
        for (int off = 1; off < 64; off <<= 1) {
            contrib += __shfl_xor(contrib, off);
            vcnt += __shfl_xor(vcnt, off);
        }
        if ((t & 63) == 0) { r1[t >> 6] = contrib; r2[t >> 6] = vcnt; }
        __syncthreads();
        if (t == 0) {
            const float sc = r1[0] + r1[1] + r1[2] + r1[3];
            const float cn = r2[0] + r2[1] + r2[2] + r2[3];
            out[0] = (cn > 0.f) ? (sc / cn) : 1.f;
        }
    }
}

extern "C" void kernel_launch(void* const* d_in, const int* in_sizes, int n_in,
                              void* d_out, int out_size, void* d_ws, size_t ws_size,
                              hipStream_t stream)
{
    const float* boxes       = (const float*)d_in[0];
    const int*   classes     = (const int*)d_in[1];
    const float* scores      = (const float*)d_in[2];
    const int*   num_objects = (const int*)d_in[3];
    const float* W1  = (const float*)d_in[4];
    const float* b1  = (const float*)d_in[5];
    const float* W2  = (const float*)d_in[6];
    const float* b2  = (const float*)d_in[7];
    const float* Wo1 = (const float*)d_in[8];
    const float* bo1 = (const float*)d_in[9];
    const float* Wo2 = (const float*)d_in[10];
    const float* bo2 = (const float*)d_in[11];
    const float* Ws1 = (const float*)d_in[12];
    const float* bs1 = (const float*)d_in[13];
    const float* Ws2 = (const float*)d_in[14];
    const float* bs2 = (const float*)d_in[15];

    float* ws  = (float*)d_ws;
    float* out = (float*)d_out;

    encode_kernel<<<2048, 256, 0, stream>>>(boxes, classes, scores,
                                            W1, b1, W2, b2, Wo1, bo1, Wo2, bo2,
                                            Ws1, ws);
    const int nblocks = 128 * 4;
    pairs_kernel<<<nblocks, 256, 0, stream>>>(bs1, Ws2, bs2, num_objects,
                                              ws, out, nblocks);
}